// Round 1
// baseline (228.678 us; speedup 1.0000x reference)
//
#include <hip/hip_runtime.h>

// Problem constants (fixed by reference):
//   z: (64,32,32,64) fp32 -> N=65536 rows, D=64
//   codebook: (1024,64) fp32 -> V=1024
// Outputs concat (float32): z_q [N*D] | tokens-as-float [N] | codebook [V*D]
constexpr int D     = 64;
constexpr int V     = 1024;
constexpr int NROWS = 65536;

// ---- pass 1: |c_v|^2 for each codeword -> d_ws ----
__global__ __launch_bounds__(256) void c2_kernel(const float* __restrict__ cb,
                                                 float* __restrict__ c2) {
    int v = blockIdx.x * blockDim.x + threadIdx.x;
    if (v < V) {
        const float4* cp = (const float4*)(cb + (size_t)v * D);
        float acc = 0.f;
#pragma unroll
        for (int i = 0; i < D / 4; ++i) {
            float4 t = cp[i];
            acc = fmaf(t.x, t.x, acc);
            acc = fmaf(t.y, t.y, acc);
            acc = fmaf(t.z, t.z, acc);
            acc = fmaf(t.w, t.w, acc);
        }
        c2[v] = acc;
    }
}

// ---- pass 2: per-row argmin over 1024 codewords ----
// Block = 256 threads = 4 waves; block covers 64 rows (one per lane).
// Wave s scans codewords [s*256, s*256+256): codeword index is wave-uniform
// -> codebook row comes in via scalar loads (s_load_dwordx16), inner loop is
// pure v_fmac_f32 against the z-row held in VGPRs.
__global__ __launch_bounds__(256, 4) void vq_main(const float* __restrict__ z,
                                                  const float* __restrict__ cb,
                                                  const float* __restrict__ c2,
                                                  float* __restrict__ zq,
                                                  float* __restrict__ tok) {
    __shared__ float s_val[4][64];
    __shared__ int   s_idx[4][64];
    __shared__ int   s_fin[64];

    const int lane = threadIdx.x & 63;
    const int wv   = __builtin_amdgcn_readfirstlane((int)(threadIdx.x >> 6));
    const int row  = blockIdx.x * 64 + lane;

    // z row -> 64 VGPRs
    float zr[D];
    {
        const float4* zp = (const float4*)(z + (size_t)row * D);
#pragma unroll
        for (int i = 0; i < D / 4; ++i) {
            float4 t = zp[i];
            zr[4 * i + 0] = t.x; zr[4 * i + 1] = t.y;
            zr[4 * i + 2] = t.z; zr[4 * i + 3] = t.w;
        }
    }
    // d1 = |z|^2 (constant per row; included so dist magnitudes/rounding
    // track the reference's d1 + d2 - d3 formulation)
    float d1 = 0.f;
#pragma unroll
    for (int i = 0; i < D; ++i) d1 = fmaf(zr[i], zr[i], d1);

    float bestDist = 3.4e38f;
    int   bestIdx  = 0;
    const int v0 = wv * (V / 4);
    for (int j = 0; j < V / 4; ++j) {
        const int v = __builtin_amdgcn_readfirstlane(v0 + j);  // force SGPR
        const float* cp = cb + (size_t)v * D;                  // uniform -> s_load
        float acc = 0.f;
#pragma unroll
        for (int d = 0; d < D; ++d)
            acc = fmaf(zr[d], cp[d], acc);
        float dist = (d1 + c2[v]) - 2.0f * acc;  // mimic (d1+d2) - d3
        if (dist < bestDist) { bestDist = dist; bestIdx = v; }  // strict < keeps first index
    }

    s_val[wv][lane] = bestDist;
    s_idx[wv][lane] = bestIdx;
    __syncthreads();

    if (wv == 0) {
        float bv = s_val[0][lane];
        int   bi = s_idx[0][lane];
#pragma unroll
        for (int s = 1; s < 4; ++s) {
            float v2 = s_val[s][lane];
            int   i2 = s_idx[s][lane];
            if (v2 < bv) { bv = v2; bi = i2; }  // s ascending: first-occurrence wins ties
        }
        tok[row]    = (float)bi;  // tokens written as float (whole out buffer is fp32)
        s_fin[lane] = bi;
    }
    __syncthreads();

    // z_q[row] = codebook[bestIdx]; 4 waves each copy 16 of the 64 floats
    {
        const int bi = s_fin[lane];
        const float4* src = (const float4*)(cb + (size_t)bi * D + wv * 16);
        float4*       dst = (float4*)(zq + (size_t)row * D + wv * 16);
#pragma unroll
        for (int i = 0; i < 4; ++i) dst[i] = src[i];
    }
}

extern "C" void kernel_launch(void* const* d_in, const int* in_sizes, int n_in,
                              void* d_out, int out_size, void* d_ws, size_t ws_size,
                              hipStream_t stream) {
    const float* z  = (const float*)d_in[0];
    const float* cb = (const float*)d_in[1];

    float* out = (float*)d_out;
    float* zq  = out;                         // [NROWS*D]
    float* tok = out + (size_t)NROWS * D;     // [NROWS]
    float* cbo = tok + NROWS;                 // [V*D]
    float* c2  = (float*)d_ws;                // 4 KiB scratch

    c2_kernel<<<(V + 255) / 256, 256, 0, stream>>>(cb, c2);
    vq_main<<<NROWS / 64, 256, 0, stream>>>(z, cb, c2, zq, tok);
    hipMemcpyAsync(cbo, cb, (size_t)V * D * sizeof(float),
                   hipMemcpyDeviceToDevice, stream);
}